// Round 6
// baseline (198.308 us; speedup 1.0000x reference)
//
#include <hip/hip_runtime.h>
#include <math.h>

#define NB 64
#define NT 512
#define HID 8192
#define NC 64
#define NH 4
#define HD 16
#define GD 64
#define IN_DIM 128
#define TSPLIT 4

typedef float f32x4 __attribute__((ext_vector_type(4)));

// ---------------------------------------------------------------------------
// Kernel 1: temporal partial-sum pooling + counter zeroing.
// H [B, T, HID] -> part[ts][b][HID] = sum over t in segment ts.
// ---------------------------------------------------------------------------
__global__ __launch_bounds__(256) void pool_kernel(const float* __restrict__ H,
                                                   float* __restrict__ part,
                                                   unsigned* __restrict__ cnt,
                                                   int ts_count) {
    const int b = blockIdx.y;
    const int ts = blockIdx.z;
    if (blockIdx.x == 0 && ts == 0 && threadIdx.x == 0) cnt[b] = 0u;

    const int idx4 = blockIdx.x * 256 + threadIdx.x;   // 0..HID/4-1
    const int rows = NT / ts_count;                     // even for ts in {1,4}
    const f32x4* src = reinterpret_cast<const f32x4*>(H + (size_t)b * NT * HID) +
                       (size_t)(ts * rows) * (HID / 4) + idx4;
    f32x4 a0 = (f32x4)0.f;
    f32x4 a1 = (f32x4)0.f;
#pragma unroll 8
    for (int t = 0; t < rows; t += 2) {
        f32x4 v0 = __builtin_nontemporal_load(&src[(size_t)t * (HID / 4)]);
        f32x4 v1 = __builtin_nontemporal_load(&src[(size_t)(t + 1) * (HID / 4)]);
        a0 += v0;
        a1 += v1;
    }
    a0 += a1;
    reinterpret_cast<f32x4*>(part + ((size_t)ts * NB + b) * HID)[idx4] = a0;
}

// ---------------------------------------------------------------------------
// Kernel 2a: fold partials -> node_inputs, embed GEMM, Wh GEMM, s1/s2.
// grid (NB, NC/16), 256 threads. Block (b, ct) owns node rows ct*16..ct*16+15.
// ---------------------------------------------------------------------------
__global__ __launch_bounds__(256) void embed_kernel(
    const float* __restrict__ part,      // [TS, B, HID]
    const float* __restrict__ W_embed,   // [GD, IN_DIM]
    const float* __restrict__ b_embed,   // [GD]
    const float* __restrict__ Wh_w,      // [NH*HD, GD]
    const float* __restrict__ a_w,       // [NH, 2*HD]
    float* __restrict__ Wh_out,          // [B, C, GD]
    float* __restrict__ s1_out,          // [B, NH, C]
    float* __restrict__ s2_out,          // [B, NH, C]
    int ts_count)
{
    __shared__ float sm_We[IN_DIM * GD];   // transposed [f][g]  32KB
    __shared__ float sm_Ww[GD * GD];       // transposed [g][ho] 16KB
    __shared__ float sm_ni[16 * IN_DIM];   // 8KB
    __shared__ float sm_nodes[16 * GD];    // 4KB
    __shared__ float sm_Wh[16 * GD];       // 4KB

    const int tid = threadIdx.x;
    const int b = blockIdx.x;
    const int ct = blockIdx.y;

    for (int idx = tid; idx < IN_DIM * GD; idx += 256) {
        int g = idx >> 7, f = idx & 127;          // W_embed[g][f]
        sm_We[f * GD + g] = W_embed[idx];
    }
    for (int idx = tid; idx < GD * GD; idx += 256) {
        int ho = idx >> 6, g = idx & 63;          // Wh_w[ho][g]
        sm_Ww[g * GD + ho] = Wh_w[idx];
    }
    // fold partial sums, float4-vectorized: 16*IN_DIM = 2048 floats = 512 float4
    for (int idx4 = tid; idx4 < 16 * IN_DIM / 4; idx4 += 256) {
        f32x4 s = (f32x4)0.f;
        for (int ts = 0; ts < ts_count; ++ts) {
            f32x4 v = reinterpret_cast<const f32x4*>(
                &part[((size_t)ts * NB + b) * HID + ct * (16 * IN_DIM)])[idx4];
            s += v;
        }
        reinterpret_cast<f32x4*>(sm_ni)[idx4] = s * (1.0f / NT);
    }
    __syncthreads();

    // nodes[c][g4..g4+3]: c = tid>>4 (broadcast ni), g4 = (tid&15)*4 (b128)
    {
        const int c = tid >> 4, g4 = (tid & 15) * 4;
        f32x4 acc = *reinterpret_cast<const f32x4*>(&b_embed[g4]);
#pragma unroll 8
        for (int f = 0; f < IN_DIM; ++f) {
            float n = sm_ni[c * IN_DIM + f];
            f32x4 w = *reinterpret_cast<const f32x4*>(&sm_We[f * GD + g4]);
            acc += n * w;
        }
        *reinterpret_cast<f32x4*>(&sm_nodes[c * GD + g4]) = acc;
    }
    __syncthreads();

    // Wh[c][o4..o4+3]
    {
        const int c = tid >> 4, o4 = (tid & 15) * 4;
        f32x4 acc = (f32x4)0.f;
#pragma unroll 8
        for (int g = 0; g < GD; ++g) {
            float n = sm_nodes[c * GD + g];
            f32x4 w = *reinterpret_cast<const f32x4*>(&sm_Ww[g * GD + o4]);
            acc += n * w;
        }
        *reinterpret_cast<f32x4*>(&sm_Wh[c * GD + o4]) = acc;
        *reinterpret_cast<f32x4*>(
            &Wh_out[((size_t)b * NC + ct * 16 + c) * GD + o4]) = acc;
    }
    __syncthreads();

    // s1/s2: threads 0..63 -> (c = tid>>2, h = tid&3)
    if (tid < 64) {
        const int c = tid >> 2, h = tid & 3;
        float a1 = 0.f, a2 = 0.f;
#pragma unroll
        for (int o = 0; o < HD; ++o) {
            float w = sm_Wh[c * GD + h * HD + o];
            a1 += w * a_w[h * 2 * HD + o];
            a2 += w * a_w[h * 2 * HD + HD + o];
        }
        s1_out[((size_t)b * NH + h) * NC + ct * 16 + c] = a1;
        s2_out[((size_t)b * NH + h) * NC + ct * 16 + c] = a2;
    }
}

// ---------------------------------------------------------------------------
// Kernel 2b: softmax attention + PV + elu + node-mean + (last block) readout.
// grid (NB, NH), 256 threads.
// ---------------------------------------------------------------------------
__global__ __launch_bounds__(256) void attn_kernel(
    const float* __restrict__ Wh_in,     // [B, C, GD]
    const float* __restrict__ s1_in,     // [B, NH, C]
    const float* __restrict__ s2_in,     // [B, NH, C]
    const float* __restrict__ Wr,        // [IN_DIM, GD]
    const float* __restrict__ br,        // [IN_DIM]
    float* __restrict__ out_attn,        // [B, NH, C, C]
    float* __restrict__ out_g,           // [B, IN_DIM]
    float* __restrict__ mean_ws,         // [B, GD]
    unsigned* __restrict__ cnt)          // [B]
{
    __shared__ float sm_Wh[NC * HD];      // [j][o]  4KB
    __shared__ float sm_s1[NC], sm_s2[NC], sm_m[NC], sm_inv[NC];
    __shared__ float sm_ho[NC * HD];      // head_out, 4KB
    __shared__ float sm_p[NC * (NC + 1)]; // p, odd-stride padded, 16.25KB
    __shared__ float sm_WrT[GD * (IN_DIM + 1)];  // readout staging, 33KB
    __shared__ float sm_mean[GD];
    __shared__ unsigned sm_last;

    const int tid = threadIdx.x;
    const int b = blockIdx.x, h = blockIdx.y;

    {   // stage Wh column block [c][h*16..h*16+16): 64 rows x 4 float4
        const int c = tid >> 2, p = tid & 3;
        *reinterpret_cast<f32x4*>(&sm_Wh[c * HD + p * 4]) =
            *reinterpret_cast<const f32x4*>(
                &Wh_in[((size_t)b * NC + c) * GD + h * HD + p * 4]);
    }
    if (tid < NC) sm_s1[tid] = s1_in[((size_t)b * NH + h) * NC + tid];
    else if (tid < 2 * NC) sm_s2[tid - NC] = s2_in[((size_t)b * NH + h) * NC + tid - NC];
    __syncthreads();

    // row stats
    if (tid < NC) {
        const float s1 = sm_s1[tid];
        float m = -1e30f;
        for (int j = 0; j < NC; ++j) {
            float x = s1 + sm_s2[j];
            float e = x > 0.f ? x : 0.2f * x;
            m = fmaxf(m, e);
        }
        float sum = 0.f;
        for (int j = 0; j < NC; ++j) {
            float x = s1 + sm_s2[j];
            float e = x > 0.f ? x : 0.2f * x;
            sum += __expf(e - m);
        }
        sm_m[tid] = m;
        sm_inv[tid] = 1.0f / sum;
    }
    __syncthreads();

    // attn writes (coalesced float4) + stash p into LDS for PV
    f32x4* attn_b = reinterpret_cast<f32x4*>(out_attn + ((size_t)b * NH + h) * NC * NC);
    for (int idx4 = tid; idx4 < NC * NC / 4; idx4 += 256) {
        const int i = idx4 >> 4, j = (idx4 & 15) * 4;
        const float s1 = sm_s1[i], m = sm_m[i], inv = sm_inv[i];
        f32x4 p;
        {
            float x = s1 + sm_s2[j + 0]; float e = x > 0.f ? x : 0.2f * x;
            p.x = __expf(e - m) * inv;
        }
        {
            float x = s1 + sm_s2[j + 1]; float e = x > 0.f ? x : 0.2f * x;
            p.y = __expf(e - m) * inv;
        }
        {
            float x = s1 + sm_s2[j + 2]; float e = x > 0.f ? x : 0.2f * x;
            p.z = __expf(e - m) * inv;
        }
        {
            float x = s1 + sm_s2[j + 3]; float e = x > 0.f ? x : 0.2f * x;
            p.w = __expf(e - m) * inv;
        }
        attn_b[idx4] = p;
        float* pr = &sm_p[i * (NC + 1) + j];
        pr[0] = p.x; pr[1] = p.y; pr[2] = p.z; pr[3] = p.w;
    }
    __syncthreads();

    // PV: thread (i = tid&63, og = tid>>6) owns 4 outputs; p from LDS
    {
        const int i = tid & 63, og = tid >> 6;
        float a0 = 0.f, a1 = 0.f, a2 = 0.f, a3 = 0.f;
        const float* prow = &sm_p[i * (NC + 1)];
        for (int j = 0; j < NC; ++j) {
            float p = prow[j];                          // 2-way bank alias: free
            const float* w = &sm_Wh[j * HD + og * 4];   // wave-uniform: broadcast
            a0 += p * w[0]; a1 += p * w[1]; a2 += p * w[2]; a3 += p * w[3];
        }
        float* ho = &sm_ho[i * HD + og * 4];
        ho[0] = a0 > 0.f ? a0 : expm1f(a0);
        ho[1] = a1 > 0.f ? a1 : expm1f(a1);
        ho[2] = a2 > 0.f ? a2 : expm1f(a2);
        ho[3] = a3 > 0.f ? a3 : expm1f(a3);
    }
    __syncthreads();

    // node-mean for this block's 16 output columns -> agent-scope release store
    if (tid < HD) {
        float s = 0.f;
        for (int i = 0; i < NC; ++i) s += sm_ho[i * HD + tid];
        __hip_atomic_store(&mean_ws[(size_t)b * GD + h * HD + tid], s * (1.0f / NC),
                           __ATOMIC_RELEASE, __HIP_MEMORY_SCOPE_AGENT);
    }
    __syncthreads();

    // last block of this b performs the readout
    if (tid == 0) {
        unsigned prev = __hip_atomic_fetch_add(&cnt[b], 1u, __ATOMIC_ACQ_REL,
                                               __HIP_MEMORY_SCOPE_AGENT);
        sm_last = (prev == NH - 1) ? 1u : 0u;
    }
    __syncthreads();
    if (sm_last) {   // block-uniform branch
        if (tid < GD)
            sm_mean[tid] = __hip_atomic_load(&mean_ws[(size_t)b * GD + tid],
                                             __ATOMIC_ACQUIRE, __HIP_MEMORY_SCOPE_AGENT);
        for (int idx = tid; idx < IN_DIM * GD; idx += 256) {
            int i = idx >> 6, g = idx & 63;           // Wr[i][g]
            sm_WrT[g * (IN_DIM + 1) + i] = Wr[idx];
        }
        __syncthreads();
        if (tid < IN_DIM) {
            float acc = br[tid];
#pragma unroll 8
            for (int g = 0; g < GD; ++g)
                acc += sm_mean[g] * sm_WrT[g * (IN_DIM + 1) + tid];
            out_g[(size_t)b * IN_DIM + tid] = fmaxf(acc, 0.f);
        }
    }
}

extern "C" void kernel_launch(void* const* d_in, const int* in_sizes, int n_in,
                              void* d_out, int out_size, void* d_ws, size_t ws_size,
                              hipStream_t stream) {
    const float* H       = (const float*)d_in[0];
    const float* W_embed = (const float*)d_in[1];
    const float* b_embed = (const float*)d_in[2];
    const float* Wh_w    = (const float*)d_in[3];
    const float* a_w     = (const float*)d_in[4];
    const float* Wr      = (const float*)d_in[5];
    const float* br      = (const float*)d_in[6];
    float* out = (float*)d_out;
    float* out_attn = out + NB * IN_DIM;

    // workspace layout
    const size_t need4 = ((size_t)TSPLIT * NB * HID + NB * NC * GD +
                          2 * NB * NH * NC + NB * GD + NB) * sizeof(float);
    const int ts = (ws_size >= need4) ? TSPLIT : 1;

    float* part    = (float*)d_ws;                        // [ts, B, HID]
    float* Wh_ws   = part + (size_t)ts * NB * HID;        // [B, C, GD]
    float* s1_ws   = Wh_ws + (size_t)NB * NC * GD;        // [B, NH, C]
    float* s2_ws   = s1_ws + (size_t)NB * NH * NC;        // [B, NH, C]
    float* mean_ws = s2_ws + (size_t)NB * NH * NC;        // [B, GD]
    unsigned* cnt  = (unsigned*)(mean_ws + (size_t)NB * GD);  // [B]

    dim3 g1(HID / 4 / 256, NB, ts);
    pool_kernel<<<g1, dim3(256), 0, stream>>>(H, part, cnt, ts);
    embed_kernel<<<dim3(NB, NC / 16), dim3(256), 0, stream>>>(
        part, W_embed, b_embed, Wh_w, a_w, Wh_ws, s1_ws, s2_ws, ts);
    attn_kernel<<<dim3(NB, NH), dim3(256), 0, stream>>>(
        Wh_ws, s1_ws, s2_ws, Wr, br, out_attn, out, mean_ws, cnt);
}

// Round 7
// 187.734 us; speedup vs baseline: 1.0563x; 1.0563x over previous
//
#include <hip/hip_runtime.h>
#include <math.h>

#define NB 64
#define NT 512
#define HID 8192
#define NC 64
#define NH 4
#define HD 16
#define GD 64
#define IN_DIM 128
#define TSPLIT 4

typedef float f32x4 __attribute__((ext_vector_type(4)));

// ---------------------------------------------------------------------------
// Kernel 1: temporal partial-sum pooling, contiguous-stream layout.
// Block (ts, b) owns the full row-panel H[b, ts*rows:(ts+1)*rows, :]:
// 1024 threads hold all HID=8192 column accumulators (2 f32x4 each) and walk
// t sequentially -> each block is one contiguous 4 MB read stream.
// ---------------------------------------------------------------------------
__global__ __launch_bounds__(1024) void pool_kernel(const float* __restrict__ H,
                                                    float* __restrict__ part,
                                                    int ts_count) {
    const int ts = blockIdx.x;
    const int b = blockIdx.y;
    const int tid = threadIdx.x;
    const int rows = NT / ts_count;
    const f32x4* src = reinterpret_cast<const f32x4*>(H + (size_t)b * NT * HID) +
                       (size_t)(ts * rows) * (HID / 4);
    f32x4 a0 = (f32x4)0.f;
    f32x4 a1 = (f32x4)0.f;
#pragma unroll 4
    for (int t = 0; t < rows; ++t) {
        f32x4 v0 = __builtin_nontemporal_load(&src[(size_t)t * (HID / 4) + tid]);
        f32x4 v1 = __builtin_nontemporal_load(&src[(size_t)t * (HID / 4) + tid + 1024]);
        a0 += v0;
        a1 += v1;
    }
    f32x4* dst = reinterpret_cast<f32x4*>(part + ((size_t)ts * NB + b) * HID);
    dst[tid] = a0;
    dst[tid + 1024] = a1;
}

// ---------------------------------------------------------------------------
// Kernel 2a: fold partials -> node_inputs, embed GEMM, Wh GEMM, s1/s2.
// grid (NB, NC/16), 256 threads. Block (b, ct) owns node rows ct*16..ct*16+15.
// ---------------------------------------------------------------------------
__global__ __launch_bounds__(256) void embed_kernel(
    const float* __restrict__ part,      // [TS, B, HID]
    const float* __restrict__ W_embed,   // [GD, IN_DIM]
    const float* __restrict__ b_embed,   // [GD]
    const float* __restrict__ Wh_w,      // [NH*HD, GD]
    const float* __restrict__ a_w,       // [NH, 2*HD]
    float* __restrict__ Wh_out,          // [B, C, GD]
    float* __restrict__ s1_out,          // [B, NH, C]
    float* __restrict__ s2_out,          // [B, NH, C]
    int ts_count)
{
    __shared__ float sm_We[IN_DIM * GD];   // transposed [f][g]  32KB
    __shared__ float sm_Ww[GD * GD];       // transposed [g][ho] 16KB
    __shared__ float sm_ni[16 * IN_DIM];   // 8KB
    __shared__ float sm_nodes[16 * GD];    // 4KB
    __shared__ float sm_Wh[16 * GD];       // 4KB

    const int tid = threadIdx.x;
    const int b = blockIdx.x;
    const int ct = blockIdx.y;

    for (int idx = tid; idx < IN_DIM * GD; idx += 256) {
        int g = idx >> 7, f = idx & 127;          // W_embed[g][f]
        sm_We[f * GD + g] = W_embed[idx];
    }
    for (int idx = tid; idx < GD * GD; idx += 256) {
        int ho = idx >> 6, g = idx & 63;          // Wh_w[ho][g]
        sm_Ww[g * GD + ho] = Wh_w[idx];
    }
    // fold partial sums, float4-vectorized: 16*IN_DIM = 2048 floats = 512 float4
    for (int idx4 = tid; idx4 < 16 * IN_DIM / 4; idx4 += 256) {
        f32x4 s = (f32x4)0.f;
        for (int ts = 0; ts < ts_count; ++ts) {
            f32x4 v = reinterpret_cast<const f32x4*>(
                &part[((size_t)ts * NB + b) * HID + ct * (16 * IN_DIM)])[idx4];
            s += v;
        }
        reinterpret_cast<f32x4*>(sm_ni)[idx4] = s * (1.0f / NT);
    }
    __syncthreads();

    // nodes[c][g4..g4+3]: c = tid>>4 (broadcast ni), g4 = (tid&15)*4 (b128)
    {
        const int c = tid >> 4, g4 = (tid & 15) * 4;
        f32x4 acc = *reinterpret_cast<const f32x4*>(&b_embed[g4]);
#pragma unroll 8
        for (int f = 0; f < IN_DIM; ++f) {
            float n = sm_ni[c * IN_DIM + f];
            f32x4 w = *reinterpret_cast<const f32x4*>(&sm_We[f * GD + g4]);
            acc += n * w;
        }
        *reinterpret_cast<f32x4*>(&sm_nodes[c * GD + g4]) = acc;
    }
    __syncthreads();

    // Wh[c][o4..o4+3]
    {
        const int c = tid >> 4, o4 = (tid & 15) * 4;
        f32x4 acc = (f32x4)0.f;
#pragma unroll 8
        for (int g = 0; g < GD; ++g) {
            float n = sm_nodes[c * GD + g];
            f32x4 w = *reinterpret_cast<const f32x4*>(&sm_Ww[g * GD + o4]);
            acc += n * w;
        }
        *reinterpret_cast<f32x4*>(&sm_Wh[c * GD + o4]) = acc;
        *reinterpret_cast<f32x4*>(
            &Wh_out[((size_t)b * NC + ct * 16 + c) * GD + o4]) = acc;
    }
    __syncthreads();

    // s1/s2: threads 0..63 -> (c = tid>>2, h = tid&3)
    if (tid < 64) {
        const int c = tid >> 2, h = tid & 3;
        float a1 = 0.f, a2 = 0.f;
#pragma unroll
        for (int o = 0; o < HD; ++o) {
            float w = sm_Wh[c * GD + h * HD + o];
            a1 += w * a_w[h * 2 * HD + o];
            a2 += w * a_w[h * 2 * HD + HD + o];
        }
        s1_out[((size_t)b * NH + h) * NC + ct * 16 + c] = a1;
        s2_out[((size_t)b * NH + h) * NC + ct * 16 + c] = a2;
    }
}

// ---------------------------------------------------------------------------
// Kernel 2b: softmax attention + PV + elu + node-mean columns.
// grid (NB, NH), 256 threads.
// ---------------------------------------------------------------------------
__global__ __launch_bounds__(256) void attn_kernel(
    const float* __restrict__ Wh_in,     // [B, C, GD]
    const float* __restrict__ s1_in,     // [B, NH, C]
    const float* __restrict__ s2_in,     // [B, NH, C]
    float* __restrict__ out_attn,        // [B, NH, C, C]
    float* __restrict__ mean_out)        // [B, GD]
{
    __shared__ float sm_Wh[NC * HD];     // [j][o]  4KB
    __shared__ float sm_s1[NC], sm_s2[NC], sm_m[NC], sm_inv[NC];
    __shared__ float sm_ho[NC * HD];     // head_out, 4KB

    const int tid = threadIdx.x;
    const int b = blockIdx.x, h = blockIdx.y;

    {   // stage Wh column block [c][h*16..h*16+16): 64 rows x 4 float4
        const int c = tid >> 2, p = tid & 3;
        *reinterpret_cast<f32x4*>(&sm_Wh[c * HD + p * 4]) =
            *reinterpret_cast<const f32x4*>(
                &Wh_in[((size_t)b * NC + c) * GD + h * HD + p * 4]);
    }
    if (tid < NC) sm_s1[tid] = s1_in[((size_t)b * NH + h) * NC + tid];
    else if (tid < 2 * NC) sm_s2[tid - NC] = s2_in[((size_t)b * NH + h) * NC + tid - NC];
    __syncthreads();

    // row stats
    if (tid < NC) {
        const float s1 = sm_s1[tid];
        float m = -1e30f;
        for (int j = 0; j < NC; ++j) {
            float x = s1 + sm_s2[j];
            float e = x > 0.f ? x : 0.2f * x;
            m = fmaxf(m, e);
        }
        float sum = 0.f;
        for (int j = 0; j < NC; ++j) {
            float x = s1 + sm_s2[j];
            float e = x > 0.f ? x : 0.2f * x;
            sum += __expf(e - m);
        }
        sm_m[tid] = m;
        sm_inv[tid] = 1.0f / sum;
    }
    __syncthreads();

    // attn writes, coalesced float4
    f32x4* attn_b = reinterpret_cast<f32x4*>(out_attn + ((size_t)b * NH + h) * NC * NC);
    for (int idx4 = tid; idx4 < NC * NC / 4; idx4 += 256) {
        const int i = idx4 >> 4, j = (idx4 & 15) * 4;
        const float s1 = sm_s1[i], m = sm_m[i], inv = sm_inv[i];
        f32x4 p;
        {
            float x = s1 + sm_s2[j + 0]; float e = x > 0.f ? x : 0.2f * x;
            p.x = __expf(e - m) * inv;
        }
        {
            float x = s1 + sm_s2[j + 1]; float e = x > 0.f ? x : 0.2f * x;
            p.y = __expf(e - m) * inv;
        }
        {
            float x = s1 + sm_s2[j + 2]; float e = x > 0.f ? x : 0.2f * x;
            p.z = __expf(e - m) * inv;
        }
        {
            float x = s1 + sm_s2[j + 3]; float e = x > 0.f ? x : 0.2f * x;
            p.w = __expf(e - m) * inv;
        }
        attn_b[idx4] = p;
    }

    // PV: thread (i = tid&63, og = tid>>6) owns 4 outputs
    {
        const int i = tid & 63, og = tid >> 6;
        const float s1 = sm_s1[i], m = sm_m[i], inv = sm_inv[i];
        float a0 = 0.f, a1 = 0.f, a2 = 0.f, a3 = 0.f;
        for (int j = 0; j < NC; ++j) {
            float x = s1 + sm_s2[j];
            float e = x > 0.f ? x : 0.2f * x;
            float p = __expf(e - m) * inv;
            const float* w = &sm_Wh[j * HD + og * 4];   // 4 distinct addrs/wave: broadcast
            a0 += p * w[0]; a1 += p * w[1]; a2 += p * w[2]; a3 += p * w[3];
        }
        float* ho = &sm_ho[i * HD + og * 4];
        ho[0] = a0 > 0.f ? a0 : expm1f(a0);
        ho[1] = a1 > 0.f ? a1 : expm1f(a1);
        ho[2] = a2 > 0.f ? a2 : expm1f(a2);
        ho[3] = a3 > 0.f ? a3 : expm1f(a3);
    }
    __syncthreads();

    // node-mean for this block's 16 output columns
    if (tid < HD) {
        float s = 0.f;
        for (int i = 0; i < NC; ++i) s += sm_ho[i * HD + tid];
        mean_out[(size_t)b * GD + h * HD + tid] = s * (1.0f / NC);
    }
}

// ---------------------------------------------------------------------------
// Kernel 2c: readout. grid (NB), 128 threads.
// ---------------------------------------------------------------------------
__global__ __launch_bounds__(128) void readout_kernel(
    const float* __restrict__ mean_in,   // [B, GD]
    const float* __restrict__ Wr,        // [IN_DIM, GD]
    const float* __restrict__ br,        // [IN_DIM]
    float* __restrict__ out_g)           // [B, IN_DIM]
{
    __shared__ float sm_mean[GD];
    __shared__ float sm_WrT[GD * (IN_DIM + 1)];   // padded transposed

    const int tid = threadIdx.x;
    const int b = blockIdx.x;

    if (tid < GD) sm_mean[tid] = mean_in[(size_t)b * GD + tid];
    for (int idx = tid; idx < IN_DIM * GD; idx += 128) {
        int i = idx >> 6, g = idx & 63;           // Wr[i][g]
        sm_WrT[g * (IN_DIM + 1) + i] = Wr[idx];
    }
    __syncthreads();

    float acc = br[tid];
#pragma unroll 8
    for (int g = 0; g < GD; ++g)
        acc += sm_mean[g] * sm_WrT[g * (IN_DIM + 1) + tid];
    out_g[(size_t)b * IN_DIM + tid] = fmaxf(acc, 0.f);
}

extern "C" void kernel_launch(void* const* d_in, const int* in_sizes, int n_in,
                              void* d_out, int out_size, void* d_ws, size_t ws_size,
                              hipStream_t stream) {
    const float* H       = (const float*)d_in[0];
    const float* W_embed = (const float*)d_in[1];
    const float* b_embed = (const float*)d_in[2];
    const float* Wh_w    = (const float*)d_in[3];
    const float* a_w     = (const float*)d_in[4];
    const float* Wr      = (const float*)d_in[5];
    const float* br      = (const float*)d_in[6];
    float* out = (float*)d_out;
    float* out_attn = out + NB * IN_DIM;

    // workspace layout
    const size_t need4 = ((size_t)TSPLIT * NB * HID + NB * NC * GD +
                          2 * NB * NH * NC + NB * GD) * sizeof(float);
    const int ts = (ws_size >= need4) ? TSPLIT : 1;

    float* part    = (float*)d_ws;                        // [ts, B, HID]
    float* Wh_ws   = part + (size_t)ts * NB * HID;        // [B, C, GD]
    float* s1_ws   = Wh_ws + (size_t)NB * NC * GD;        // [B, NH, C]
    float* s2_ws   = s1_ws + (size_t)NB * NH * NC;        // [B, NH, C]
    float* mean_ws = s2_ws + (size_t)NB * NH * NC;        // [B, GD]

    dim3 g1(ts, NB);
    pool_kernel<<<g1, dim3(1024), 0, stream>>>(H, part, ts);
    embed_kernel<<<dim3(NB, NC / 16), dim3(256), 0, stream>>>(
        part, W_embed, b_embed, Wh_w, a_w, Wh_ws, s1_ws, s2_ws, ts);
    attn_kernel<<<dim3(NB, NH), dim3(256), 0, stream>>>(
        Wh_ws, s1_ws, s2_ws, out_attn, mean_ws);
    readout_kernel<<<dim3(NB), dim3(128), 0, stream>>>(mean_ws, Wr, br, out);
}

// Round 8
// 184.716 us; speedup vs baseline: 1.0736x; 1.0163x over previous
//
#include <hip/hip_runtime.h>
#include <math.h>

#define NB 64
#define NT 512
#define HID 8192
#define NC 64
#define NH 4
#define HD 16
#define GD 64
#define IN_DIM 128
#define TSPLIT 4

// padded strides (keep 16B alignment for f32x4: stride*4 % 16 == 0)
#define SWE 68    // sm_We row stride  (GD+4)
#define SWW 68    // sm_Ww row stride  (GD+4)
#define SNI 132   // sm_ni row stride  (IN_DIM+4)
#define SND 68    // sm_nodes row stride
#define SWH 68    // sm_Wh row stride

typedef float f32x4 __attribute__((ext_vector_type(4)));

// ---------------------------------------------------------------------------
// Kernel 1: temporal partial-sum pooling, contiguous-stream layout.
// Block (ts, b) owns the full row-panel H[b, ts*rows:(ts+1)*rows, :]:
// 1024 threads hold all HID=8192 column accumulators (2 f32x4 each) and walk
// t sequentially -> each block is one contiguous 4 MB read stream.
// ---------------------------------------------------------------------------
__global__ __launch_bounds__(1024) void pool_kernel(const float* __restrict__ H,
                                                    float* __restrict__ part,
                                                    int ts_count) {
    const int ts = blockIdx.x;
    const int b = blockIdx.y;
    const int tid = threadIdx.x;
    const int rows = NT / ts_count;
    const f32x4* src = reinterpret_cast<const f32x4*>(H + (size_t)b * NT * HID) +
                       (size_t)(ts * rows) * (HID / 4);
    f32x4 a0 = (f32x4)0.f;
    f32x4 a1 = (f32x4)0.f;
#pragma unroll 4
    for (int t = 0; t < rows; ++t) {
        f32x4 v0 = __builtin_nontemporal_load(&src[(size_t)t * (HID / 4) + tid]);
        f32x4 v1 = __builtin_nontemporal_load(&src[(size_t)t * (HID / 4) + tid + 1024]);
        a0 += v0;
        a1 += v1;
    }
    f32x4* dst = reinterpret_cast<f32x4*>(part + ((size_t)ts * NB + b) * HID);
    dst[tid] = a0;
    dst[tid + 1024] = a1;
}

// ---------------------------------------------------------------------------
// Kernel 2a: fold partials -> node_inputs, embed GEMM, Wh GEMM, s1/s2.
// grid (NB, NC/16), 256 threads. Block (b, ct) owns node rows ct*16..ct*16+15.
// All LDS tiles pad-strided: transpose-staging writes 64-way -> 8-way,
// GEMM broadcast reads 4-way -> conflict-free.
// ---------------------------------------------------------------------------
__global__ __launch_bounds__(256) void embed_kernel(
    const float* __restrict__ part,      // [TS, B, HID]
    const float* __restrict__ W_embed,   // [GD, IN_DIM]
    const float* __restrict__ b_embed,   // [GD]
    const float* __restrict__ Wh_w,      // [NH*HD, GD]
    const float* __restrict__ a_w,       // [NH, 2*HD]
    float* __restrict__ Wh_out,          // [B, C, GD]
    float* __restrict__ s1_out,          // [B, NH, C]
    float* __restrict__ s2_out,          // [B, NH, C]
    int ts_count)
{
    __shared__ float sm_We[IN_DIM * SWE];  // transposed [f][g]
    __shared__ float sm_Ww[GD * SWW];      // transposed [g][ho]
    __shared__ float sm_ni[16 * SNI];
    __shared__ float sm_nodes[16 * SND];
    __shared__ float sm_Wh[16 * SWH];

    const int tid = threadIdx.x;
    const int b = blockIdx.x;
    const int ct = blockIdx.y;

    for (int idx = tid; idx < IN_DIM * GD; idx += 256) {
        int g = idx >> 7, f = idx & 127;          // W_embed[g][f]
        sm_We[f * SWE + g] = W_embed[idx];        // bank (4f+g)%32: 8-way
    }
    for (int idx = tid; idx < GD * GD; idx += 256) {
        int ho = idx >> 6, g = idx & 63;          // Wh_w[ho][g]
        sm_Ww[g * SWW + ho] = Wh_w[idx];          // bank (4g+ho)%32: 8-way
    }
    // fold partial sums, float4-vectorized: 16*IN_DIM = 2048 floats = 512 f32x4
    for (int idx4 = tid; idx4 < 16 * IN_DIM / 4; idx4 += 256) {
        const int c = idx4 >> 5, f4 = (idx4 & 31) << 2;
        f32x4 s = (f32x4)0.f;
        for (int ts = 0; ts < ts_count; ++ts) {
            f32x4 v = reinterpret_cast<const f32x4*>(
                &part[((size_t)ts * NB + b) * HID + ct * (16 * IN_DIM)])[idx4];
            s += v;
        }
        *reinterpret_cast<f32x4*>(&sm_ni[c * SNI + f4]) = s * (1.0f / NT);
    }
    __syncthreads();

    // nodes[c][g4..g4+3]: c = tid>>4 (conflict-free bcast), g4 = (tid&15)*4
    {
        const int c = tid >> 4, g4 = (tid & 15) * 4;
        f32x4 acc = *reinterpret_cast<const f32x4*>(&b_embed[g4]);
#pragma unroll 8
        for (int f = 0; f < IN_DIM; ++f) {
            float n = sm_ni[c * SNI + f];
            f32x4 w = *reinterpret_cast<const f32x4*>(&sm_We[f * SWE + g4]);
            acc += n * w;
        }
        *reinterpret_cast<f32x4*>(&sm_nodes[c * SND + g4]) = acc;
    }
    __syncthreads();

    // Wh[c][o4..o4+3]
    {
        const int c = tid >> 4, o4 = (tid & 15) * 4;
        f32x4 acc = (f32x4)0.f;
#pragma unroll 8
        for (int g = 0; g < GD; ++g) {
            float n = sm_nodes[c * SND + g];
            f32x4 w = *reinterpret_cast<const f32x4*>(&sm_Ww[g * SWW + o4]);
            acc += n * w;
        }
        *reinterpret_cast<f32x4*>(&sm_Wh[c * SWH + o4]) = acc;
        *reinterpret_cast<f32x4*>(
            &Wh_out[((size_t)b * NC + ct * 16 + c) * GD + o4]) = acc;
    }
    __syncthreads();

    // s1/s2: threads 0..63 -> (c = tid>>2, h = tid&3)
    if (tid < 64) {
        const int c = tid >> 2, h = tid & 3;
        float a1 = 0.f, a2 = 0.f;
#pragma unroll
        for (int o = 0; o < HD; ++o) {
            float w = sm_Wh[c * SWH + h * HD + o];
            a1 += w * a_w[h * 2 * HD + o];
            a2 += w * a_w[h * 2 * HD + HD + o];
        }
        s1_out[((size_t)b * NH + h) * NC + ct * 16 + c] = a1;
        s2_out[((size_t)b * NH + h) * NC + ct * 16 + c] = a2;
    }
}

// ---------------------------------------------------------------------------
// Kernel 2b: softmax attention + PV + elu + node-mean columns.
// grid (NB, NH), 256 threads. Row stats parallelized across all 256 threads.
// ---------------------------------------------------------------------------
__global__ __launch_bounds__(256) void attn_kernel(
    const float* __restrict__ Wh_in,     // [B, C, GD]
    const float* __restrict__ s1_in,     // [B, NH, C]
    const float* __restrict__ s2_in,     // [B, NH, C]
    float* __restrict__ out_attn,        // [B, NH, C, C]
    float* __restrict__ mean_out)        // [B, GD]
{
    __shared__ float sm_Wh[NC * HD];     // [j][o]  4KB
    __shared__ float sm_s1[NC], sm_s2[NC], sm_m[NC], sm_inv[NC];
    __shared__ float sm_pm[4][NC];       // partial max
    __shared__ float sm_ps[4][NC];       // partial sum
    __shared__ float sm_ho[NC * HD];     // head_out, 4KB

    const int tid = threadIdx.x;
    const int b = blockIdx.x, h = blockIdx.y;

    {   // stage Wh column block [c][h*16..h*16+16): 64 rows x 4 float4
        const int c = tid >> 2, p = tid & 3;
        *reinterpret_cast<f32x4*>(&sm_Wh[c * HD + p * 4]) =
            *reinterpret_cast<const f32x4*>(
                &Wh_in[((size_t)b * NC + c) * GD + h * HD + p * 4]);
    }
    if (tid < NC) sm_s1[tid] = s1_in[((size_t)b * NH + h) * NC + tid];
    else if (tid < 2 * NC) sm_s2[tid - NC] = s2_in[((size_t)b * NH + h) * NC + tid - NC];
    __syncthreads();

    // row stats, parallel: thread (i = tid&63, q = tid>>6) covers j in [16q,16q+16)
    {
        const int i = tid & 63, q = tid >> 6;
        const float s1 = sm_s1[i];
        float pm = -1e30f;
#pragma unroll
        for (int jj = 0; jj < 16; ++jj) {
            float x = s1 + sm_s2[q * 16 + jj];
            float e = x > 0.f ? x : 0.2f * x;
            pm = fmaxf(pm, e);
        }
        sm_pm[q][i] = pm;
        __syncthreads();
        const float m = fmaxf(fmaxf(sm_pm[0][i], sm_pm[1][i]),
                              fmaxf(sm_pm[2][i], sm_pm[3][i]));
        float ps = 0.f;
#pragma unroll
        for (int jj = 0; jj < 16; ++jj) {
            float x = s1 + sm_s2[q * 16 + jj];
            float e = x > 0.f ? x : 0.2f * x;
            ps += __expf(e - m);
        }
        sm_ps[q][i] = ps;
        __syncthreads();
        if (tid < NC) {
            sm_m[tid] = m;   // q==0 thread has same m
            sm_inv[tid] = 1.0f / (((sm_ps[0][tid] + sm_ps[1][tid]) +
                                   (sm_ps[2][tid] + sm_ps[3][tid])));
        }
    }
    __syncthreads();

    // attn writes, coalesced float4
    f32x4* attn_b = reinterpret_cast<f32x4*>(out_attn + ((size_t)b * NH + h) * NC * NC);
    for (int idx4 = tid; idx4 < NC * NC / 4; idx4 += 256) {
        const int i = idx4 >> 4, j = (idx4 & 15) * 4;
        const float s1 = sm_s1[i], m = sm_m[i], inv = sm_inv[i];
        f32x4 p;
        {
            float x = s1 + sm_s2[j + 0]; float e = x > 0.f ? x : 0.2f * x;
            p.x = __expf(e - m) * inv;
        }
        {
            float x = s1 + sm_s2[j + 1]; float e = x > 0.f ? x : 0.2f * x;
            p.y = __expf(e - m) * inv;
        }
        {
            float x = s1 + sm_s2[j + 2]; float e = x > 0.f ? x : 0.2f * x;
            p.z = __expf(e - m) * inv;
        }
        {
            float x = s1 + sm_s2[j + 3]; float e = x > 0.f ? x : 0.2f * x;
            p.w = __expf(e - m) * inv;
        }
        attn_b[idx4] = p;
    }

    // PV: thread (i = tid&63, og = tid>>6) owns 4 outputs
    {
        const int i = tid & 63, og = tid >> 6;
        const float s1 = sm_s1[i], m = sm_m[i], inv = sm_inv[i];
        float a0 = 0.f, a1 = 0.f, a2 = 0.f, a3 = 0.f;
        for (int j = 0; j < NC; ++j) {
            float x = s1 + sm_s2[j];
            float e = x > 0.f ? x : 0.2f * x;
            float p = __expf(e - m) * inv;
            const float* w = &sm_Wh[j * HD + og * 4];   // wave-uniform: broadcast
            a0 += p * w[0]; a1 += p * w[1]; a2 += p * w[2]; a3 += p * w[3];
        }
        float* ho = &sm_ho[i * HD + og * 4];
        ho[0] = a0 > 0.f ? a0 : expm1f(a0);
        ho[1] = a1 > 0.f ? a1 : expm1f(a1);
        ho[2] = a2 > 0.f ? a2 : expm1f(a2);
        ho[3] = a3 > 0.f ? a3 : expm1f(a3);
    }
    __syncthreads();

    // node-mean for this block's 16 output columns
    if (tid < HD) {
        float s = 0.f;
        for (int i = 0; i < NC; ++i) s += sm_ho[i * HD + tid];
        mean_out[(size_t)b * GD + h * HD + tid] = s * (1.0f / NC);
    }
}

// ---------------------------------------------------------------------------
// Kernel 2c: readout. grid (NB), 128 threads.
// ---------------------------------------------------------------------------
__global__ __launch_bounds__(128) void readout_kernel(
    const float* __restrict__ mean_in,   // [B, GD]
    const float* __restrict__ Wr,        // [IN_DIM, GD]
    const float* __restrict__ br,        // [IN_DIM]
    float* __restrict__ out_g)           // [B, IN_DIM]
{
    __shared__ float sm_mean[GD];
    __shared__ float sm_WrT[GD * (IN_DIM + 1)];   // padded transposed

    const int tid = threadIdx.x;
    const int b = blockIdx.x;

    if (tid < GD) sm_mean[tid] = mean_in[(size_t)b * GD + tid];
    for (int idx = tid; idx < IN_DIM * GD; idx += 128) {
        int i = idx >> 6, g = idx & 63;           // Wr[i][g]
        sm_WrT[g * (IN_DIM + 1) + i] = Wr[idx];
    }
    __syncthreads();

    float acc = br[tid];
#pragma unroll 8
    for (int g = 0; g < GD; ++g)
        acc += sm_mean[g] * sm_WrT[g * (IN_DIM + 1) + tid];
    out_g[(size_t)b * IN_DIM + tid] = fmaxf(acc, 0.f);
}

extern "C" void kernel_launch(void* const* d_in, const int* in_sizes, int n_in,
                              void* d_out, int out_size, void* d_ws, size_t ws_size,
                              hipStream_t stream) {
    const float* H       = (const float*)d_in[0];
    const float* W_embed = (const float*)d_in[1];
    const float* b_embed = (const float*)d_in[2];
    const float* Wh_w    = (const float*)d_in[3];
    const float* a_w     = (const float*)d_in[4];
    const float* Wr      = (const float*)d_in[5];
    const float* br      = (const float*)d_in[6];
    float* out = (float*)d_out;
    float* out_attn = out + NB * IN_DIM;

    // workspace layout
    const size_t need4 = ((size_t)TSPLIT * NB * HID + NB * NC * GD +
                          2 * NB * NH * NC + NB * GD) * sizeof(float);
    const int ts = (ws_size >= need4) ? TSPLIT : 1;

    float* part    = (float*)d_ws;                        // [ts, B, HID]
    float* Wh_ws   = part + (size_t)ts * NB * HID;        // [B, C, GD]
    float* s1_ws   = Wh_ws + (size_t)NB * NC * GD;        // [B, NH, C]
    float* s2_ws   = s1_ws + (size_t)NB * NH * NC;        // [B, NH, C]
    float* mean_ws = s2_ws + (size_t)NB * NH * NC;        // [B, GD]

    dim3 g1(ts, NB);
    pool_kernel<<<g1, dim3(1024), 0, stream>>>(H, part, ts);
    embed_kernel<<<dim3(NB, NC / 16), dim3(256), 0, stream>>>(
        part, W_embed, b_embed, Wh_w, a_w, Wh_ws, s1_ws, s2_ws, ts);
    attn_kernel<<<dim3(NB, NH), dim3(256), 0, stream>>>(
        Wh_ws, s1_ws, s2_ws, out_attn, mean_ws);
    readout_kernel<<<dim3(NB), dim3(128), 0, stream>>>(mean_ws, Wr, br, out);
}